// Round 14
// baseline (30.385 us; speedup 1.0000x reference)
//
#include <hip/hip_runtime.h>
#include <math.h>

#define NB 64
#define V_FULL 6890
#define V_HAND 250
#define V_LOOP 20
#define N_FACES 500
#define FPAD 512      // faces padded with degenerate (v0,v0,v0) -> omega = 0
#define NPTS 251      // V_HAND + 1 (appended loop-mean vertex)
#define NPTS_PAD 256  // pad rows (duplicates of vertex 0)
#define DROW 36       // dist-table row stride (f32): 16B-aligned
#define KSPLIT 32     // lanes per point-quad (face-loop split)
#define PCHUNK 32     // points per block (4 consecutive per thread)
#define NCHUNK 8      // 256 / PCHUNK

struct F3 { float x, y, z; };
typedef float v2f __attribute__((ext_vector_type(2)));

// ---- VOP3P packed-f32 helpers (forced via inline asm; hipcc scalarizes
// ext_vector math otherwise). op_sel broadcasts let per-face scalars feed
// both elements with no splat movs.
__device__ __forceinline__ v2f pk_fma(v2f a, v2f b, v2f c) {
    v2f d; asm("v_pk_fma_f32 %0, %1, %2, %3" : "=v"(d) : "v"(a), "v"(b), "v"(c)); return d;
}
__device__ __forceinline__ v2f pk_fma_s1lo(v2f a, v2f b, v2f c) {  // b.lo -> both
    v2f d; asm("v_pk_fma_f32 %0, %1, %2, %3 op_sel:[0,0,0] op_sel_hi:[1,0,1]"
               : "=v"(d) : "v"(a), "v"(b), "v"(c)); return d;
}
__device__ __forceinline__ v2f pk_fma_s1hi(v2f a, v2f b, v2f c) {  // b.hi -> both
    v2f d; asm("v_pk_fma_f32 %0, %1, %2, %3 op_sel:[0,1,0] op_sel_hi:[1,1,1]"
               : "=v"(d) : "v"(a), "v"(b), "v"(c)); return d;
}
__device__ __forceinline__ v2f pk_fma_s1lo_s2hi(v2f a, v2f b, v2f c) { // b.lo, c.hi
    v2f d; asm("v_pk_fma_f32 %0, %1, %2, %3 op_sel:[0,0,1] op_sel_hi:[1,0,1]"
               : "=v"(d) : "v"(a), "v"(b), "v"(c)); return d;
}
__device__ __forceinline__ v2f pk_mul(v2f a, v2f b) {
    v2f d; asm("v_pk_mul_f32 %0, %1, %2" : "=v"(d) : "v"(a), "v"(b)); return d;
}
__device__ __forceinline__ v2f pk_add(v2f a, v2f b) {
    v2f d; asm("v_pk_add_f32 %0, %1, %2" : "=v"(d) : "v"(a), "v"(b)); return d;
}
__device__ __forceinline__ v2f pk_add_s1lo(v2f a, v2f b) {  // b.lo -> both
    v2f d; asm("v_pk_add_f32 %0, %1, %2 op_sel:[0,0] op_sel_hi:[1,0]"
               : "=v"(d) : "v"(a), "v"(b)); return d;
}
__device__ __forceinline__ v2f pk_add_s1hi(v2f a, v2f b) {  // b.hi -> both
    v2f d; asm("v_pk_add_f32 %0, %1, %2 op_sel:[0,1] op_sel_hi:[1,1]"
               : "=v"(d) : "v"(a), "v"(b)); return d;
}

// Pair atan2: interior packed via VOP3P, scalar only for max/min/rcp/select.
// Octant fold to z in [0,1], degree-11 minimax poly, err ~1.4e-5 rad.
__device__ __forceinline__ v2f atan2_pair(v2f y, v2f x,
                                          v2f C5, v2f C4, v2f C3, v2f C2,
                                          v2f C1, v2f C0, v2f NEG1,
                                          v2f PIO2v, v2f PIv) {
    float ax0 = __builtin_fabsf(x.x), ay0 = __builtin_fabsf(y.x);
    float ax1 = __builtin_fabsf(x.y), ay1 = __builtin_fabsf(y.y);
    float mx0 = fmaxf(fmaxf(ax0, ay0), 1e-38f);
    float mx1 = fmaxf(fmaxf(ax1, ay1), 1e-38f);
    float mn0 = fminf(ax0, ay0);
    float mn1 = fminf(ax1, ay1);
    v2f z;
    z.x = mn0 * __builtin_amdgcn_rcpf(mx0);
    z.y = mn1 * __builtin_amdgcn_rcpf(mx1);
    v2f zz = pk_mul(z, z);
    v2f p  = pk_fma(zz, C5, C4);
    p = pk_fma(zz, p, C3);
    p = pk_fma(zz, p, C2);
    p = pk_fma(zz, p, C1);
    p = pk_fma(zz, p, C0);
    v2f r  = pk_mul(z, p);
    v2f rq = pk_fma(r, NEG1, PIO2v);          // PI/2 - r
    float r0 = (ay0 > ax0) ? rq.x : r.x;
    float r1 = (ay1 > ax1) ? rq.y : r.y;
    v2f rr; rr.x = r0; rr.y = r1;
    v2f rp = pk_fma(rr, NEG1, PIv);           // PI - r
    r0 = (x.x < 0.0f) ? rp.x : r0;
    r1 = (x.y < 0.0f) ? rp.y : r1;
    v2f out;
    out.x = copysignf(r0, y.x);
    out.y = copysignf(r1, y.y);
    return out;
}

// Grid (NB, 2, NCHUNK) = 1024 blocks. Block 256 = 8 quads x 32 lanes.
// Quad q owns points 4q..4q+3; lane k handles faces k, k+32, ...
// Inner loop: det = 2D + p.(-2N); dots via law of cosines from f32 dist
// table + negated squared edge lengths; no sqrt; all element-wise math
// forced onto v_pk_*_f32.
__global__ __launch_bounds__(256) void hand_pen_kernel(
    const float* __restrict__ verts,     // [NB][V_FULL][3]
    const int* __restrict__ inds_l,
    const int* __restrict__ inds_r,
    const int* __restrict__ loop_l,
    const int* __restrict__ loop_r,
    const int* __restrict__ faces_l,     // [N_FACES][3]
    const int* __restrict__ faces_r,
    float* __restrict__ partial)         // [NB][2][NCHUNK]
{
    const int b   = blockIdx.x;
    const int dir = blockIdx.y;
    const int z   = blockIdx.z;
    const int tid = threadIdx.x;
    const int q   = tid >> 5;           // point-quad 0..7
    const int k   = tid & 31;           // face-split lane 0..31
    const int q4  = q * 4;

    __shared__ float4 sov[NPTS_PAD];          // other-hand verts (4 KB)
    __shared__ float  sdist[NPTS_PAD][DROW];  // |p - v| table (36 KB)
    __shared__ float4 snd[FPAD];              // (-2Nx,-2Ny,-2Nz, 2D) (8 KB)
    __shared__ float4 se2[FPAD];              // (-e01,-e12,-e20, idx) (8 KB)
    __shared__ F3     spts[PCHUNK];
    __shared__ float  wave_part[4];

    const float* vb = verts + (size_t)b * V_FULL * 3;
    const int* pind  = (dir == 0) ? inds_l  : inds_r;
    const int* oind  = (dir == 0) ? inds_r  : inds_l;
    const int* ploop = (dir == 0) ? loop_l  : loop_r;
    const int* oloop = (dir == 0) ? loop_r  : loop_l;
    const int* fcs   = (dir == 0) ? faces_r : faces_l;

    // ---- Phase 1: gather other-hand verts (+pad) and this block's 32 points
    {
        int i = tid;
        int go = (i < V_HAND) ? oind[i] : oind[0];   // pad rows = vertex 0
        float4 v = make_float4(vb[go * 3 + 0], vb[go * 3 + 1], vb[go * 3 + 2], 0.f);
        if (i != V_HAND) sov[i] = v;                 // slot 250 = mean, below
    }
    if (tid < 32) {   // other-hand loop mean (20 live lanes, shuffle reduce)
        float sx = 0.f, sy = 0.f, sz = 0.f;
        if (tid < V_LOOP) {
            int gi = oloop[tid];
            sx = vb[gi * 3 + 0]; sy = vb[gi * 3 + 1]; sz = vb[gi * 3 + 2];
        }
        #pragma unroll
        for (int off = 1; off < 32; off <<= 1) {
            sx += __shfl_xor(sx, off);
            sy += __shfl_xor(sy, off);
            sz += __shfl_xor(sz, off);
        }
        if (tid == 0) {
            const float inv = 1.0f / (float)V_LOOP;
            sov[V_HAND] = make_float4(sx * inv, sy * inv, sz * inv, 0.f);
        }
    }
    if (tid >= 64 && tid < 64 + PCHUNK) {   // this block's query points
        int myp = z * PCHUNK + (tid - 64);
        if (myp < V_HAND) {
            int gp = pind[myp];
            F3 qv; qv.x = vb[gp * 3 + 0]; qv.y = vb[gp * 3 + 1]; qv.z = vb[gp * 3 + 2];
            spts[tid - 64] = qv;
        } else if (myp > V_HAND) {
            F3 qv = {0.f, 0.f, 0.f};
            spts[tid - 64] = qv;
        }
    }
    if (tid >= 96 && tid < 128) {  // this-hand loop mean -> point V_HAND
        int l = tid - 96;
        float sx = 0.f, sy = 0.f, sz = 0.f;
        if (l < V_LOOP) {
            int gi = ploop[l];
            sx = vb[gi * 3 + 0]; sy = vb[gi * 3 + 1]; sz = vb[gi * 3 + 2];
        }
        #pragma unroll
        for (int off = 1; off < 32; off <<= 1) {
            sx += __shfl_xor(sx, off);
            sy += __shfl_xor(sy, off);
            sz += __shfl_xor(sz, off);
        }
        if (tid == 96 && V_HAND >= z * PCHUNK && V_HAND < z * PCHUNK + PCHUNK) {
            const float inv = 1.0f / (float)V_LOOP;
            F3 qv; qv.x = sx * inv; qv.y = sy * inv; qv.z = sz * inv;
            spts[V_HAND - z * PCHUNK] = qv;
        }
    }
    __syncthreads();

    // ---- Phase 2a: f32 distance table. Thread t builds row t.
    {
        float4 v = sov[tid];
        #pragma unroll
        for (int c = 0; c < 8; ++c) {
            float4 dd;
            F3 p0v = spts[c * 4 + 0];
            F3 p1v = spts[c * 4 + 1];
            F3 p2v = spts[c * 4 + 2];
            F3 p3v = spts[c * 4 + 3];
            float dx, dy, dz;
            dx = v.x - p0v.x; dy = v.y - p0v.y; dz = v.z - p0v.z;
            dd.x = __builtin_amdgcn_sqrtf(dx * dx + dy * dy + dz * dz);
            dx = v.x - p1v.x; dy = v.y - p1v.y; dz = v.z - p1v.z;
            dd.y = __builtin_amdgcn_sqrtf(dx * dx + dy * dy + dz * dz);
            dx = v.x - p2v.x; dy = v.y - p2v.y; dz = v.z - p2v.z;
            dd.z = __builtin_amdgcn_sqrtf(dx * dx + dy * dy + dz * dz);
            dx = v.x - p3v.x; dy = v.y - p3v.y; dz = v.z - p3v.z;
            dd.w = __builtin_amdgcn_sqrtf(dx * dx + dy * dy + dz * dz);
            *reinterpret_cast<float4*>(&sdist[tid][c * 4]) = dd;
        }
    }

    // ---- Phase 2b: per-face constants: (-2N, 2D) and NEGATED squared edge
    // lengths + packed indices. Pad faces (v0,v0,v0) -> N=D=0, e=0 -> omega 0.
    for (int i = tid; i < FPAD; i += 256) {
        float4 v0, v1, v2;
        int i0 = 0, i1 = 0, i2 = 0;
        if (i < N_FACES) {
            i0 = fcs[3 * i + 0]; i1 = fcs[3 * i + 1]; i2 = fcs[3 * i + 2];
        }
        v0 = sov[i0]; v1 = sov[i1]; v2 = sov[i2];
        float ux = v1.y * v2.z - v1.z * v2.y;
        float uy = v1.z * v2.x - v1.x * v2.z;
        float uz = v1.x * v2.y - v1.y * v2.x;
        float Nx = ux + (v2.y * v0.z - v2.z * v0.y) + (v0.y * v1.z - v0.z * v1.y);
        float Ny = uy + (v2.z * v0.x - v2.x * v0.z) + (v0.z * v1.x - v0.x * v1.z);
        float Nz = uz + (v2.x * v0.y - v2.y * v0.x) + (v0.x * v1.y - v0.y * v1.x);
        float D  = v0.x * ux + v0.y * uy + v0.z * uz;
        snd[i] = make_float4(-2.f * Nx, -2.f * Ny, -2.f * Nz, 2.f * D);
        float ex, ey, ez, e01, e12, e20;
        ex = v0.x - v1.x; ey = v0.y - v1.y; ez = v0.z - v1.z;
        e01 = ex * ex + ey * ey + ez * ez;
        ex = v1.x - v2.x; ey = v1.y - v2.y; ez = v1.z - v2.z;
        e12 = ex * ex + ey * ey + ez * ez;
        ex = v2.x - v0.x; ey = v2.y - v0.y; ez = v2.z - v0.z;
        e20 = ex * ex + ey * ey + ez * ez;
        unsigned int u = (unsigned)i0 | ((unsigned)i1 << 8) | ((unsigned)i2 << 16);
        se2[i] = make_float4(-e01, -e12, -e20, __uint_as_float(u));
    }
    __syncthreads();

    // This thread's 4 consecutive points as two float2 pairs
    const v2f pxA = { spts[q4 + 0].x, spts[q4 + 1].x };
    const v2f pyA = { spts[q4 + 0].y, spts[q4 + 1].y };
    const v2f pzA = { spts[q4 + 0].z, spts[q4 + 1].z };
    const v2f pxB = { spts[q4 + 2].x, spts[q4 + 3].x };
    const v2f pyB = { spts[q4 + 2].y, spts[q4 + 3].y };
    const v2f pzB = { spts[q4 + 2].z, spts[q4 + 3].z };
    const int pbase = z * PCHUNK + q4;

    // Loop-invariant packed constants (materialized once, hoisted)
    const v2f C5 = {-0.01172120f, -0.01172120f};
    const v2f C4 = { 0.05265332f,  0.05265332f};
    const v2f C3 = {-0.11643287f, -0.11643287f};
    const v2f C2 = { 0.19354346f,  0.19354346f};
    const v2f C1 = {-0.33262347f, -0.33262347f};
    const v2f C0 = { 0.99997726f,  0.99997726f};
    const v2f NEG1  = {-1.f, -1.f};
    const v2f PIO2v = {1.57079632679490f, 1.57079632679490f};
    const v2f PIv   = {3.14159265358979f, 3.14159265358979f};

    // ---- Winding: 16 uniform iters; per face 5 b128 reads; all element-wise
    // math on v_pk_*_f32 with op_sel broadcasts for per-face scalars.
    v2f wsA = {0.f, 0.f}, wsB = {0.f, 0.f};
    #pragma unroll 2
    for (int f = k; f < FPAD; f += KSPLIT) {
        float4 nd = snd[f];
        float4 e2 = se2[f];
        v2f ndxy = { nd.x, nd.y };
        v2f ndzw = { nd.z, nd.w };
        v2f eab  = { e2.x, e2.y };
        v2f ecw  = { e2.z, e2.w };
        unsigned int u = __float_as_uint(e2.w);
        const float4 da4 = *reinterpret_cast<const float4*>(&sdist[u & 255u][q4]);
        const float4 db4 = *reinterpret_cast<const float4*>(&sdist[(u >> 8) & 255u][q4]);
        const float4 dc4 = *reinterpret_cast<const float4*>(&sdist[(u >> 16) & 255u][q4]);

        v2f daA = { da4.x, da4.y }, daB = { da4.z, da4.w };
        v2f dbA = { db4.x, db4.y }, dbB = { db4.z, db4.w };
        v2f dcA = { dc4.x, dc4.y }, dcB = { dc4.z, dc4.w };

        // det = 2D + p.(-2N): 3 pk fma with op_sel broadcasts
        v2f tA = pk_fma_s1lo_s2hi(pzA, ndzw, ndzw);   // pz*(-2Nz) + 2D
        tA = pk_fma_s1hi(pyA, ndxy, tA);              // + py*(-2Ny)
        v2f detA = pk_fma_s1lo(pxA, ndxy, tA);        // + px*(-2Nx)
        v2f tB = pk_fma_s1lo_s2hi(pzB, ndzw, ndzw);
        tB = pk_fma_s1hi(pyB, ndxy, tB);
        v2f detB = pk_fma_s1lo(pxB, ndxy, tB);

        // law-of-cosines dots (edge^2 pre-negated -> pure pk_add)
        v2f a2A = pk_mul(daA, daA), b2A = pk_mul(dbA, dbA), c2A = pk_mul(dcA, dcA);
        v2f a2B = pk_mul(daB, daB), b2B = pk_mul(dbB, dbB), c2B = pk_mul(dcB, dcB);
        v2f ab2A = pk_add_s1lo(pk_add(a2A, b2A), eab);
        v2f bc2A = pk_add_s1hi(pk_add(b2A, c2A), eab);
        v2f ca2A = pk_add_s1lo(pk_add(c2A, a2A), ecw);
        v2f ab2B = pk_add_s1lo(pk_add(a2B, b2B), eab);
        v2f bc2B = pk_add_s1hi(pk_add(b2B, c2B), eab);
        v2f ca2B = pk_add_s1lo(pk_add(c2B, a2B), ecw);

        v2f t2A = pk_fma(pk_add(daA, daA), dbA, ab2A);
        v2f uA  = pk_fma(bc2A, daA, pk_mul(ca2A, dbA));
        v2f denA = pk_fma(t2A, dcA, uA);
        v2f t2B = pk_fma(pk_add(daB, daB), dbB, ab2B);
        v2f uB  = pk_fma(bc2B, daB, pk_mul(ca2B, dbB));
        v2f denB = pk_fma(t2B, dcB, uB);

        wsA = pk_add(wsA, atan2_pair(detA, denA, C5, C4, C3, C2, C1, C0, NEG1, PIO2v, PIv));
        wsB = pk_add(wsB, atan2_pair(detB, denB, C5, C4, C3, C2, C1, C0, NEG1, PIO2v, PIv));
    }

    // ---- Min-dist: scan the dist table (affine rows, b128).
    float d0 = 1e30f, d1 = 1e30f, d2m = 1e30f, d3 = 1e30f;
    for (int j = k; j < NPTS_PAD; j += KSPLIT) {
        float4 dd = *reinterpret_cast<const float4*>(&sdist[j][q4]);
        d0  = fminf(d0,  dd.x);
        d1  = fminf(d1,  dd.y);
        d2m = fminf(d2m, dd.z);
        d3  = fminf(d3,  dd.w);
    }

    float ws0 = wsA.x, ws1 = wsA.y, ws2 = wsB.x, ws3 = wsB.y;

    // Reduce across the 32-lane group (xor <= 16 stays in wave half)
    #pragma unroll
    for (int off = 1; off <= 16; off <<= 1) {
        ws0 += __shfl_xor(ws0, off);
        ws1 += __shfl_xor(ws1, off);
        ws2 += __shfl_xor(ws2, off);
        ws3 += __shfl_xor(ws3, off);
        d0  = fminf(d0,  __shfl_xor(d0,  off));
        d1  = fminf(d1,  __shfl_xor(d1,  off));
        d2m = fminf(d2m, __shfl_xor(d2m, off));
        d3  = fminf(d3,  __shfl_xor(d3,  off));
    }

    float contrib = 0.0f;
    if (k == 0) {
        if (pbase + 0 < NPTS && ws0 > (float)M_PI) contrib += d0;
        if (pbase + 1 < NPTS && ws1 > (float)M_PI) contrib += d1;
        if (pbase + 2 < NPTS && ws2 > (float)M_PI) contrib += d2m;
        if (pbase + 3 < NPTS && ws3 > (float)M_PI) contrib += d3;
    }

    // Block reduction: wave64 shuffle then 4 partials in LDS
    for (int off = 32; off > 0; off >>= 1)
        contrib += __shfl_down(contrib, off);
    if ((tid & 63) == 0) wave_part[tid >> 6] = contrib;
    __syncthreads();
    if (tid == 0)
        partial[(b * 2 + dir) * NCHUNK + z] =
            wave_part[0] + wave_part[1] + wave_part[2] + wave_part[3];
}

__global__ void combine_kernel(const float* __restrict__ partial, float* __restrict__ out)
{
    int i = threadIdx.x;
    if (i < NB) {
        float s = 0.0f;
        for (int j = 0; j < 2 * NCHUNK; ++j)
            s += partial[i * 2 * NCHUNK + j];
        out[i] = s;
    }
}

extern "C" void kernel_launch(void* const* d_in, const int* in_sizes, int n_in,
                              void* d_out, int out_size, void* d_ws, size_t ws_size,
                              hipStream_t stream) {
    const float* verts  = (const float*)d_in[0];
    const int* inds_l   = (const int*)d_in[1];
    const int* inds_r   = (const int*)d_in[2];
    const int* loop_l   = (const int*)d_in[3];
    const int* loop_r   = (const int*)d_in[4];
    const int* faces_l  = (const int*)d_in[5];
    const int* faces_r  = (const int*)d_in[6];
    float* out = (float*)d_out;
    float* partial = (float*)d_ws;  // NB*2*NCHUNK floats

    hand_pen_kernel<<<dim3(NB, 2, NCHUNK), 256, 0, stream>>>(
        verts, inds_l, inds_r, loop_l, loop_r, faces_l, faces_r, partial);
    combine_kernel<<<1, 64, 0, stream>>>(partial, out);
}